// Round 3
// baseline (606.384 us; speedup 1.0000x reference)
//
#include <hip/hip_runtime.h>

#define L_SEQ 8192
#define NP 8192            // complex points per pipeline (half-spectrum path)
#define NTH 512
#define HID 256
#define PIDX(i) ((i) + ((i) >> 5))
#define LDS_SZ 8448        // PIDX(8191)+1 = 8447, rounded

#define ANG16 3.83495196971410315e-4f   // 2*pi/16384
#define ANG8  7.66990393942820630e-4f   // 2*pi/8192

__device__ __forceinline__ float2 cmul(float2 a, float2 b) {
  return make_float2(a.x*b.x - a.y*b.y, a.x*b.y + a.y*b.x);
}
__device__ __forceinline__ float2 cadd(float2 a, float2 b){ return make_float2(a.x+b.x, a.y+b.y); }
__device__ __forceinline__ float2 csub(float2 a, float2 b){ return make_float2(a.x-b.x, a.y-b.y); }

__device__ __forceinline__ void bf4_fwd(float2 a0, float2 a1, float2 a2, float2 a3,
                                        float2& o0, float2& o1, float2& o2, float2& o3) {
  float2 t0 = cadd(a0,a2), t1 = csub(a0,a2), t2 = cadd(a1,a3), t3 = csub(a1,a3);
  o0 = cadd(t0,t2);
  o2 = csub(t0,t2);
  o1 = make_float2(t1.x + t3.y, t1.y - t3.x);   // t1 - i*t3
  o3 = make_float2(t1.x - t3.y, t1.y + t3.x);   // t1 + i*t3
}
__device__ __forceinline__ void bf4_inv(float2 c0, float2 c1, float2 c2, float2 c3,
                                        float2& o0, float2& o1, float2& o2, float2& o3) {
  float2 u0 = cadd(c0,c2), u2 = csub(c0,c2), u1 = cadd(c1,c3);
  float2 v3 = make_float2(c3.y - c1.y, c1.x - c3.x);  // i*(c1-c3)
  o0 = cadd(u0,u1); o2 = csub(u0,u1); o1 = cadd(u2,v3); o3 = csub(u2,v3);
}

// omega16^a for a=0..3 (fwd_pair/inv_pair level twiddles)
__device__ __constant__ const float W16C[4] = {1.0f, 0.92387953251128674f, 0.70710678118654752f, 0.38268343236508977f};
__device__ __constant__ const float W16S[4] = {0.0f, -0.38268343236508977f, -0.70710678118654752f, -0.92387953251128674f};
// omega16^e for e=0..9 (fused middle, exponent a*b)
__device__ __constant__ const float C16[10] = {1.0f, 0.92387953251128674f, 0.70710678118654752f, 0.38268343236508977f,
                                               0.0f, -0.38268343236508977f, -0.70710678118654752f, -0.92387953251128674f,
                                               -1.0f, -0.92387953251128674f};
__device__ __constant__ const float S16[10] = {0.0f, -0.38268343236508977f, -0.70710678118654752f, -0.92387953251128674f,
                                               -1.0f, -0.92387953251128674f, -0.70710678118654752f, -0.38268343236508977f,
                                               0.0f, 0.38268343236508977f};

// Fused pair of forward DIF radix-4 stages (m = MB, then m = MB/4) over NP=8192.
// One 16-point superbutterfly per thread (8192/16 = 512 = NTH).
template<int MB>
__device__ __forceinline__ void fwd_pair(float2* __restrict__ X, int tid) {
  const int MQ = MB / 4;
  int g = tid / MQ;
  int i2 = tid - g*MQ;
  int base = g*4*MB + i2;
  float2 e[4][4];
  #pragma unroll
  for (int a = 0; a < 4; ++a)
    #pragma unroll
    for (int b = 0; b < 4; ++b)
      e[a][b] = X[PIDX(base + a*MQ + b*MB)];
  float sb, cb;
  __sincosf(-6.2831853071795864769f * (float)i2 / (float)(4*MB), &sb, &cb);
  float2 wb = make_float2(cb, sb);
  float2 f[4][4];
  #pragma unroll
  for (int a = 0; a < 4; ++a) {
    float2 wa = cmul(wb, make_float2(W16C[a], W16S[a]));
    float2 w2 = cmul(wa, wa), w3 = cmul(w2, wa);
    float2 o0,o1,o2,o3;
    bf4_fwd(e[a][0], e[a][1], e[a][2], e[a][3], o0,o1,o2,o3);
    f[a][0] = o0; f[a][1] = cmul(o1,wa); f[a][2] = cmul(o2,w2); f[a][3] = cmul(o3,w3);
  }
  float2 wp = cmul(wb,wb); wp = cmul(wp,wp);
  float2 wp2 = cmul(wp,wp), wp3 = cmul(wp2,wp);
  #pragma unroll
  for (int b = 0; b < 4; ++b) {
    float2 o0,o1,o2,o3;
    bf4_fwd(f[0][b], f[1][b], f[2][b], f[3][b], o0,o1,o2,o3);
    X[PIDX(base + 0*MQ + b*MB)] = o0;
    X[PIDX(base + 1*MQ + b*MB)] = cmul(o1,wp);
    X[PIDX(base + 2*MQ + b*MB)] = cmul(o2,wp2);
    X[PIDX(base + 3*MQ + b*MB)] = cmul(o3,wp3);
  }
}

// Fused pair of inverse DIT radix-4 stages (m = MB/4, then m = MB).
template<int MB>
__device__ __forceinline__ void inv_pair(float2* __restrict__ X, int tid) {
  const int MQ = MB / 4;
  int g = tid / MQ;
  int i2 = tid - g*MQ;
  int base = g*4*MB + i2;
  float2 e[4][4];
  #pragma unroll
  for (int a = 0; a < 4; ++a)
    #pragma unroll
    for (int b = 0; b < 4; ++b)
      e[a][b] = X[PIDX(base + a*MQ + b*MB)];
  float sb, cb;
  __sincosf(6.2831853071795864769f * (float)i2 / (float)(4*MB), &sb, &cb);
  float2 wb = make_float2(cb, sb);
  float2 wq = cmul(wb,wb); wq = cmul(wq,wq);
  float2 wq2 = cmul(wq,wq), wq3 = cmul(wq2,wq);
  float2 f[4][4];
  #pragma unroll
  for (int b = 0; b < 4; ++b) {
    float2 c0 = e[0][b];
    float2 c1 = cmul(e[1][b], wq);
    float2 c2 = cmul(e[2][b], wq2);
    float2 c3 = cmul(e[3][b], wq3);
    float2 o0,o1,o2,o3;
    bf4_inv(c0,c1,c2,c3, o0,o1,o2,o3);
    f[0][b]=o0; f[1][b]=o1; f[2][b]=o2; f[3][b]=o3;
  }
  #pragma unroll
  for (int a = 0; a < 4; ++a) {
    float2 W1 = cmul(wb, make_float2(W16C[a], -W16S[a]));
    float2 W2 = cmul(W1,W1), W3 = cmul(W2,W1);
    float2 c0 = f[a][0];
    float2 c1 = cmul(f[a][1], W1);
    float2 c2 = cmul(f[a][2], W2);
    float2 c3 = cmul(f[a][3], W3);
    float2 o0,o1,o2,o3;
    bf4_inv(c0,c1,c2,c3, o0,o1,o2,o3);
    X[PIDX(base + a*MQ + 0*MB)] = o0;
    X[PIDX(base + a*MQ + 1*MB)] = o1;
    X[PIDX(base + a*MQ + 2*MB)] = o2;
    X[PIDX(base + a*MQ + 3*MB)] = o3;
  }
}

// forward stages m=4 then m=1, compile-time twiddles, on 16 consecutive points
__device__ __forceinline__ void fwd41(float2 P[16]) {
  #pragma unroll
  for (int i = 0; i < 4; ++i) {
    float2 o0,o1,o2,o3;
    bf4_fwd(P[i], P[i+4], P[i+8], P[i+12], o0,o1,o2,o3);
    P[i]    = o0;
    P[i+4]  = cmul(o1, make_float2(C16[i],   S16[i]));
    P[i+8]  = cmul(o2, make_float2(C16[2*i], S16[2*i]));
    P[i+12] = cmul(o3, make_float2(C16[3*i], S16[3*i]));
  }
  #pragma unroll
  for (int q = 0; q < 4; ++q) {
    float2 o0,o1,o2,o3;
    bf4_fwd(P[4*q],P[4*q+1],P[4*q+2],P[4*q+3], o0,o1,o2,o3);
    P[4*q]=o0; P[4*q+1]=o1; P[4*q+2]=o2; P[4*q+3]=o3;
  }
}
// inverse stages m=1 then m=4 (exact inverse of fwd41, unnormalized x16)
__device__ __forceinline__ void inv14(float2 P[16]) {
  #pragma unroll
  for (int q = 0; q < 4; ++q) {
    float2 o0,o1,o2,o3;
    bf4_inv(P[4*q],P[4*q+1],P[4*q+2],P[4*q+3], o0,o1,o2,o3);
    P[4*q]=o0; P[4*q+1]=o1; P[4*q+2]=o2; P[4*q+3]=o3;
  }
  #pragma unroll
  for (int i = 0; i < 4; ++i) {
    float2 c0 = P[i];
    float2 c1 = cmul(P[i+4],  make_float2(C16[i],   -S16[i]));
    float2 c2 = cmul(P[i+8],  make_float2(C16[2*i], -S16[2*i]));
    float2 c3 = cmul(P[i+12], make_float2(C16[3*i], -S16[3*i]));
    float2 o0,o1,o2,o3;
    bf4_inv(c0,c1,c2,c3, o0,o1,o2,o3);
    P[i]=o0; P[i+4]=o1; P[i+8]=o2; P[i+12]=o3;
  }
}

// ---------------- filter generation (unchanged) ----------------
__global__ __launch_bounds__(256) void kgen_kernel(
    const float* __restrict__ W1, const float* __restrict__ b1, const float* __restrict__ fq0,
    const float* __restrict__ W2, const float* __restrict__ b2, const float* __restrict__ fq1,
    const float* __restrict__ W3, const float* __restrict__ b3, const float* __restrict__ fq2,
    const float* __restrict__ Wout, const float* __restrict__ Dv, float* __restrict__ kbuf) {
  int l = blockIdx.x * 256 + threadIdx.x;
  int c0 = blockIdx.y * 32;
  float t = (float)l * (1.0f / (float)(L_SEQ - 1));
  float w = 6.2831853071795864769f * (float)l / (float)L_SEQ;
  float z0 = t;
  float z1 = __cosf(1e-4f * w);
  float z2 = __cosf(w);
  float z3 = -__sinf(1e-4f * w);
  float z4 = -__sinf(w);
  float ha[64];
  #pragma unroll
  for (int o = 0; o < 64; ++o) {
    float acc = b1[o] + z0*W1[o*5+0] + z1*W1[o*5+1] + z2*W1[o*5+2]
                      + z3*W1[o*5+3] + z4*W1[o*5+4];
    ha[o] = __sinf(fq0[o] * acc);
  }
  float hb[64];
  #pragma unroll
  for (int p = 0; p < 64; ++p) {
    float acc = b2[p];
    #pragma unroll
    for (int o = 0; o < 64; ++o) acc += ha[o] * W2[p*64+o];
    hb[p] = __sinf(fq1[p] * acc);
  }
  #pragma unroll
  for (int p = 0; p < 64; ++p) {
    float acc = b3[p];
    #pragma unroll
    for (int o = 0; o < 64; ++o) acc += hb[o] * W3[p*64+o];
    ha[p] = __sinf(fq2[p] * acc);   // ha now holds h3
  }
  const float mind = -3.0701134573253945f;    // ln(0.01)/1.5
  const float maxd = -15.350567286626972f;    // ln(0.01)/0.3
  for (int jj = 0; jj < 32; ++jj) {
    int c = c0 + jj;
    float acc = 0.f;
    #pragma unroll
    for (int o = 0; o < 64; ++o) acc += ha[o] * Wout[c*64+o];
    float delta = mind + (maxd - mind) * ((float)c * (1.0f/255.0f));
    float dec = __expf(-t * fabsf(delta)) + 0.05f;
    float v = acc * dec;
    if (l == 0) v += Dv[c];                   // conv(u, k + D*delta) = conv + D*u
    kbuf[(size_t)c * L_SEQ + l] = v;
  }
}

// ---------------- kernel spectra: KfA = FFT8192(k)/16384, KfB = FFT8192(k*w16384^n)/16384 ----------------
__global__ __launch_bounds__(NTH, 2) void kf_kernel(const float* __restrict__ kbuf,
                                                    float2* __restrict__ Kf) {
  __shared__ float2 X[LDS_SZ];
  int c = blockIdx.x;
  int tid = threadIdx.x;
  const float* kr = kbuf + (size_t)c * L_SEQ;
  const float sc = 1.0f / 16384.0f;

  #pragma unroll
  for (int pipe = 0; pipe < 2; ++pipe) {
    // prolog: optional pre-twiddle (pipe B), then 8192-level radix-2
    #pragma unroll
    for (int r = 0; r < 2; ++r) {
      int n = 4*tid + 2048*r;
      float4 lo = *(const float4*)(kr + n);
      float4 hi = *(const float4*)(kr + n + 4096);
      #pragma unroll
      for (int j = 0; j < 4; ++j) {
        float klo = ((const float*)&lo)[j];
        float khi = ((const float*)&hi)[j];
        float2 vlo, vhi, w8;
        if (pipe == 0) {
          float sn, cn; __sincosf(-ANG8 * (float)(n+j), &sn, &cn);
          vlo = make_float2(klo, 0.f);
          vhi = make_float2(khi, 0.f);
          w8 = make_float2(cn, sn);
        } else {
          float sn, cn; __sincosf(-ANG16 * (float)(n+j), &sn, &cn);
          vlo = make_float2(klo*cn, klo*sn);          // klo * w16^n
          vhi = make_float2(khi*sn, -khi*cn);         // khi * w16^n * (-i)
          w8 = cmul(make_float2(cn, sn), make_float2(cn, sn));
        }
        X[PIDX(n+j)]        = cadd(vlo, vhi);
        X[PIDX(n+j+4096)]   = cmul(csub(vlo, vhi), w8);
      }
    }
    __syncthreads();
    fwd_pair<1024>(X, tid); __syncthreads();
    fwd_pair<64>(X, tid);   __syncthreads();
    // fused fwd(4,1) + scaled store
    {
      float2 P[16];
      int base = tid*16;
      #pragma unroll
      for (int j = 0; j < 16; ++j) P[j] = X[PIDX(base+j)];
      fwd41(P);
      float2* out = Kf + (size_t)c * 16384 + pipe*8192 + base;
      #pragma unroll
      for (int j = 0; j < 16; ++j) out[j] = make_float2(P[j].x*sc, P[j].y*sc);
    }
    __syncthreads();
  }
}

// ---------------- conv: two 8192 pipelines (odd bins then even bins), reg-stash combine ----------------
__global__ __launch_bounds__(NTH, 4) void conv_kernel(const float* __restrict__ x,
                                                      const float2* __restrict__ Kf,
                                                      float* __restrict__ y) {
  __shared__ float2 X[LDS_SZ];
  int c = blockIdx.x;
  int p = blockIdx.y;
  int tid = threadIdx.x;
  const float* u0 = x + ((size_t)p       * HID + c) * L_SEQ;
  const float* u1 = x + ((size_t)(p + 4) * HID + c) * L_SEQ;
  const float2* KA = Kf + (size_t)c * 16384;
  const float2* KB = KA + 8192;
  float* y0 = y + ((size_t)p       * HID + c) * L_SEQ;
  float* y1 = y + ((size_t)(p + 4) * HID + c) * L_SEQ;

  float2 stash[16];   // w16384bar^n * IU_B at this thread's output positions

  // ================= pipeline B (odd bins) =================
  #pragma unroll
  for (int r = 0; r < 2; ++r) {
    int n = 4*tid + 2048*r;
    float4 a0 = *(const float4*)(u0 + n);
    float4 a1 = *(const float4*)(u1 + n);
    float4 b0 = *(const float4*)(u0 + n + 4096);
    float4 b1 = *(const float4*)(u1 + n + 4096);
    #pragma unroll
    for (int j = 0; j < 4; ++j) {
      float sn, cn; __sincosf(-ANG16 * (float)(n+j), &sn, &cn);
      float2 w16 = make_float2(cn, sn);
      float2 vlo = cmul(make_float2(((const float*)&a0)[j], ((const float*)&a1)[j]), w16);
      float2 vhi = cmul(make_float2(((const float*)&b0)[j], ((const float*)&b1)[j]),
                        make_float2(sn, -cn));        // * w16 * (-i)
      float2 w8 = cmul(w16, w16);
      X[PIDX(n+j)]      = cadd(vlo, vhi);
      X[PIDX(n+j+4096)] = cmul(csub(vlo, vhi), w8);
    }
  }
  __syncthreads();
  fwd_pair<1024>(X, tid); __syncthreads();
  fwd_pair<64>(X, tid);   __syncthreads();
  {
    float2 P[16];
    int base = tid*16;
    #pragma unroll
    for (int j = 0; j < 16; ++j) P[j] = X[PIDX(base+j)];
    fwd41(P);
    #pragma unroll
    for (int j = 0; j < 16; ++j) P[j] = cmul(P[j], KB[base+j]);
    inv14(P);
    #pragma unroll
    for (int j = 0; j < 16; ++j) X[PIDX(base+j)] = P[j];
  }
  __syncthreads();
  inv_pair<64>(X, tid);   __syncthreads();
  inv_pair<1024>(X, tid); __syncthreads();
  // epilog B: within-pipeline radix-2 inverse + cross twiddle -> stash
  #pragma unroll
  for (int r = 0; r < 2; ++r) {
    int n = 4*tid + 2048*r;
    #pragma unroll
    for (int j = 0; j < 4; ++j) {
      float2 P = X[PIDX(n+j)], Q = X[PIDX(n+j+4096)];
      float sn, cn; __sincosf(ANG16 * (float)(n+j), &sn, &cn);   // w16bar^n
      float2 w16b = make_float2(cn, sn);
      float2 w8b = cmul(w16b, w16b);
      float2 t = cmul(Q, w8b);
      float2 IUlo = cadd(P, t);
      float2 IUhi = csub(P, t);
      stash[r*4+j]     = cmul(IUlo, w16b);
      stash[8 + r*4+j] = cmul(IUhi, make_float2(-w16b.y, w16b.x));  // * i*w16bar^n
    }
  }
  __syncthreads();   // all reads done before pipeline A overwrites LDS

  // ================= pipeline A (even bins) =================
  #pragma unroll
  for (int r = 0; r < 2; ++r) {
    int n = 4*tid + 2048*r;
    float4 a0 = *(const float4*)(u0 + n);
    float4 a1 = *(const float4*)(u1 + n);
    float4 b0 = *(const float4*)(u0 + n + 4096);
    float4 b1 = *(const float4*)(u1 + n + 4096);
    #pragma unroll
    for (int j = 0; j < 4; ++j) {
      float sn, cn; __sincosf(-ANG8 * (float)(n+j), &sn, &cn);
      float2 vlo = make_float2(((const float*)&a0)[j], ((const float*)&a1)[j]);
      float2 vhi = make_float2(((const float*)&b0)[j], ((const float*)&b1)[j]);
      X[PIDX(n+j)]      = cadd(vlo, vhi);
      X[PIDX(n+j+4096)] = cmul(csub(vlo, vhi), make_float2(cn, sn));
    }
  }
  __syncthreads();
  fwd_pair<1024>(X, tid); __syncthreads();
  fwd_pair<64>(X, tid);   __syncthreads();
  {
    float2 P[16];
    int base = tid*16;
    #pragma unroll
    for (int j = 0; j < 16; ++j) P[j] = X[PIDX(base+j)];
    fwd41(P);
    #pragma unroll
    for (int j = 0; j < 16; ++j) P[j] = cmul(P[j], KA[base+j]);
    inv14(P);
    #pragma unroll
    for (int j = 0; j < 16; ++j) X[PIDX(base+j)] = P[j];
  }
  __syncthreads();
  inv_pair<64>(X, tid);   __syncthreads();
  inv_pair<1024>(X, tid); __syncthreads();
  // epilog A: radix-2 inverse + add stash, store y
  #pragma unroll
  for (int r = 0; r < 2; ++r) {
    int n = 4*tid + 2048*r;
    float4 w00, w01, w10, w11;
    #pragma unroll
    for (int j = 0; j < 4; ++j) {
      float2 P = X[PIDX(n+j)], Q = X[PIDX(n+j+4096)];
      float sn, cn; __sincosf(ANG8 * (float)(n+j), &sn, &cn);    // w8bar^n
      float2 t = cmul(Q, make_float2(cn, sn));
      float2 lo = cadd(cadd(P, t), stash[r*4+j]);
      float2 hi = cadd(csub(P, t), stash[8 + r*4+j]);
      ((float*)&w00)[j] = lo.x; ((float*)&w01)[j] = lo.y;
      ((float*)&w10)[j] = hi.x; ((float*)&w11)[j] = hi.y;
    }
    *(float4*)(y0 + n)        = w00;
    *(float4*)(y1 + n)        = w01;
    *(float4*)(y0 + n + 4096) = w10;
    *(float4*)(y1 + n + 4096) = w11;
  }
}

extern "C" void kernel_launch(void* const* d_in, const int* in_sizes, int n_in,
                              void* d_out, int out_size, void* d_ws, size_t ws_size,
                              hipStream_t stream) {
  const float* x    = (const float*)d_in[0];
  const float* W1   = (const float*)d_in[1];
  const float* b1   = (const float*)d_in[2];
  const float* fq0  = (const float*)d_in[3];
  const float* W2   = (const float*)d_in[4];
  const float* b2   = (const float*)d_in[5];
  const float* fq1  = (const float*)d_in[6];
  const float* W3   = (const float*)d_in[7];
  const float* b3   = (const float*)d_in[8];
  const float* fq2  = (const float*)d_in[9];
  const float* Wout = (const float*)d_in[10];
  const float* Dv   = (const float*)d_in[11];

  float*  kbuf = (float*)d_ws;                                                  // 8 MB
  float2* Kf   = (float2*)((char*)d_ws + (size_t)HID * L_SEQ * sizeof(float));  // +32 MB
  float*  y    = (float*)d_out;

  kgen_kernel<<<dim3(32, 8), 256, 0, stream>>>(W1,b1,fq0,W2,b2,fq1,W3,b3,fq2,Wout,Dv,kbuf);
  kf_kernel  <<<dim3(256),   NTH, 0, stream>>>(kbuf, Kf);
  conv_kernel<<<dim3(256,4), NTH, 0, stream>>>(x, Kf, y);
}

// Round 4
// 399.566 us; speedup vs baseline: 1.5176x; 1.5176x over previous
//
#include <hip/hip_runtime.h>

#define L_SEQ 8192
#define NTH 512
#define HID 256
#define PIDX(i) ((i) + ((i) >> 5))
#define LDS_SZ 8448        // PIDX(8191)+1 = 8447, rounded

#define ANG16 3.83495196971410315e-4f   // 2*pi/16384
#define ANG8  7.66990393942820630e-4f   // 2*pi/8192

__device__ __forceinline__ float2 cmul(float2 a, float2 b) {
  return make_float2(a.x*b.x - a.y*b.y, a.x*b.y + a.y*b.x);
}
__device__ __forceinline__ float2 cadd(float2 a, float2 b){ return make_float2(a.x+b.x, a.y+b.y); }
__device__ __forceinline__ float2 csub(float2 a, float2 b){ return make_float2(a.x-b.x, a.y-b.y); }

__device__ __forceinline__ void bf4_fwd(float2 a0, float2 a1, float2 a2, float2 a3,
                                        float2& o0, float2& o1, float2& o2, float2& o3) {
  float2 t0 = cadd(a0,a2), t1 = csub(a0,a2), t2 = cadd(a1,a3), t3 = csub(a1,a3);
  o0 = cadd(t0,t2);
  o2 = csub(t0,t2);
  o1 = make_float2(t1.x + t3.y, t1.y - t3.x);   // t1 - i*t3
  o3 = make_float2(t1.x - t3.y, t1.y + t3.x);   // t1 + i*t3
}
__device__ __forceinline__ void bf4_inv(float2 c0, float2 c1, float2 c2, float2 c3,
                                        float2& o0, float2& o1, float2& o2, float2& o3) {
  float2 u0 = cadd(c0,c2), u2 = csub(c0,c2), u1 = cadd(c1,c3);
  float2 v3 = make_float2(c3.y - c1.y, c1.x - c3.x);  // i*(c1-c3)
  o0 = cadd(u0,u1); o2 = csub(u0,u1); o1 = cadd(u2,v3); o3 = csub(u2,v3);
}

// omega16^a for a=0..3 (fwd_pair/inv_pair level twiddles)
__device__ __constant__ const float W16C[4] = {1.0f, 0.92387953251128674f, 0.70710678118654752f, 0.38268343236508977f};
__device__ __constant__ const float W16S[4] = {0.0f, -0.38268343236508977f, -0.70710678118654752f, -0.92387953251128674f};
// omega16^e for e=0..9 (fused middle, exponent a*b)
__device__ __constant__ const float C16[10] = {1.0f, 0.92387953251128674f, 0.70710678118654752f, 0.38268343236508977f,
                                               0.0f, -0.38268343236508977f, -0.70710678118654752f, -0.92387953251128674f,
                                               -1.0f, -0.92387953251128674f};
__device__ __constant__ const float S16[10] = {0.0f, -0.38268343236508977f, -0.70710678118654752f, -0.92387953251128674f,
                                               -1.0f, -0.92387953251128674f, -0.70710678118654752f, -0.38268343236508977f,
                                               0.0f, 0.38268343236508977f};

// Fused pair of forward DIF radix-4 stages (m = MB, then m = MB/4) over 8192.
// One 16-point superbutterfly per thread (8192/16 = 512 = NTH).
template<int MB>
__device__ __forceinline__ void fwd_pair(float2* __restrict__ X, int tid) {
  const int MQ = MB / 4;
  int g = tid / MQ;
  int i2 = tid - g*MQ;
  int base = g*4*MB + i2;
  float2 e[4][4];
  #pragma unroll
  for (int a = 0; a < 4; ++a)
    #pragma unroll
    for (int b = 0; b < 4; ++b)
      e[a][b] = X[PIDX(base + a*MQ + b*MB)];
  float sb, cb;
  __sincosf(-6.2831853071795864769f * (float)i2 / (float)(4*MB), &sb, &cb);
  float2 wb = make_float2(cb, sb);
  float2 f[4][4];
  #pragma unroll
  for (int a = 0; a < 4; ++a) {
    float2 wa = cmul(wb, make_float2(W16C[a], W16S[a]));
    float2 w2 = cmul(wa, wa), w3 = cmul(w2, wa);
    float2 o0,o1,o2,o3;
    bf4_fwd(e[a][0], e[a][1], e[a][2], e[a][3], o0,o1,o2,o3);
    f[a][0] = o0; f[a][1] = cmul(o1,wa); f[a][2] = cmul(o2,w2); f[a][3] = cmul(o3,w3);
  }
  float2 wp = cmul(wb,wb); wp = cmul(wp,wp);
  float2 wp2 = cmul(wp,wp), wp3 = cmul(wp2,wp);
  #pragma unroll
  for (int b = 0; b < 4; ++b) {
    float2 o0,o1,o2,o3;
    bf4_fwd(f[0][b], f[1][b], f[2][b], f[3][b], o0,o1,o2,o3);
    X[PIDX(base + 0*MQ + b*MB)] = o0;
    X[PIDX(base + 1*MQ + b*MB)] = cmul(o1,wp);
    X[PIDX(base + 2*MQ + b*MB)] = cmul(o2,wp2);
    X[PIDX(base + 3*MQ + b*MB)] = cmul(o3,wp3);
  }
}

// Fused pair of inverse DIT radix-4 stages (m = MB/4, then m = MB).
template<int MB>
__device__ __forceinline__ void inv_pair(float2* __restrict__ X, int tid) {
  const int MQ = MB / 4;
  int g = tid / MQ;
  int i2 = tid - g*MQ;
  int base = g*4*MB + i2;
  float2 e[4][4];
  #pragma unroll
  for (int a = 0; a < 4; ++a)
    #pragma unroll
    for (int b = 0; b < 4; ++b)
      e[a][b] = X[PIDX(base + a*MQ + b*MB)];
  float sb, cb;
  __sincosf(6.2831853071795864769f * (float)i2 / (float)(4*MB), &sb, &cb);
  float2 wb = make_float2(cb, sb);
  float2 wq = cmul(wb,wb); wq = cmul(wq,wq);
  float2 wq2 = cmul(wq,wq), wq3 = cmul(wq2,wq);
  float2 f[4][4];
  #pragma unroll
  for (int b = 0; b < 4; ++b) {
    float2 c0 = e[0][b];
    float2 c1 = cmul(e[1][b], wq);
    float2 c2 = cmul(e[2][b], wq2);
    float2 c3 = cmul(e[3][b], wq3);
    float2 o0,o1,o2,o3;
    bf4_inv(c0,c1,c2,c3, o0,o1,o2,o3);
    f[0][b]=o0; f[1][b]=o1; f[2][b]=o2; f[3][b]=o3;
  }
  #pragma unroll
  for (int a = 0; a < 4; ++a) {
    float2 W1 = cmul(wb, make_float2(W16C[a], -W16S[a]));
    float2 W2 = cmul(W1,W1), W3 = cmul(W2,W1);
    float2 c0 = f[a][0];
    float2 c1 = cmul(f[a][1], W1);
    float2 c2 = cmul(f[a][2], W2);
    float2 c3 = cmul(f[a][3], W3);
    float2 o0,o1,o2,o3;
    bf4_inv(c0,c1,c2,c3, o0,o1,o2,o3);
    X[PIDX(base + a*MQ + 0*MB)] = o0;
    X[PIDX(base + a*MQ + 1*MB)] = o1;
    X[PIDX(base + a*MQ + 2*MB)] = o2;
    X[PIDX(base + a*MQ + 3*MB)] = o3;
  }
}

// forward stages m=4 then m=1, compile-time twiddles, on 16 consecutive points
__device__ __forceinline__ void fwd41(float2 P[16]) {
  #pragma unroll
  for (int i = 0; i < 4; ++i) {
    float2 o0,o1,o2,o3;
    bf4_fwd(P[i], P[i+4], P[i+8], P[i+12], o0,o1,o2,o3);
    P[i]    = o0;
    P[i+4]  = cmul(o1, make_float2(C16[i],   S16[i]));
    P[i+8]  = cmul(o2, make_float2(C16[2*i], S16[2*i]));
    P[i+12] = cmul(o3, make_float2(C16[3*i], S16[3*i]));
  }
  #pragma unroll
  for (int q = 0; q < 4; ++q) {
    float2 o0,o1,o2,o3;
    bf4_fwd(P[4*q],P[4*q+1],P[4*q+2],P[4*q+3], o0,o1,o2,o3);
    P[4*q]=o0; P[4*q+1]=o1; P[4*q+2]=o2; P[4*q+3]=o3;
  }
}
// inverse stages m=1 then m=4 (exact inverse of fwd41, unnormalized x16)
__device__ __forceinline__ void inv14(float2 P[16]) {
  #pragma unroll
  for (int q = 0; q < 4; ++q) {
    float2 o0,o1,o2,o3;
    bf4_inv(P[4*q],P[4*q+1],P[4*q+2],P[4*q+3], o0,o1,o2,o3);
    P[4*q]=o0; P[4*q+1]=o1; P[4*q+2]=o2; P[4*q+3]=o3;
  }
  #pragma unroll
  for (int i = 0; i < 4; ++i) {
    float2 c0 = P[i];
    float2 c1 = cmul(P[i+4],  make_float2(C16[i],   -S16[i]));
    float2 c2 = cmul(P[i+8],  make_float2(C16[2*i], -S16[2*i]));
    float2 c3 = cmul(P[i+12], make_float2(C16[3*i], -S16[3*i]));
    float2 o0,o1,o2,o3;
    bf4_inv(c0,c1,c2,c3, o0,o1,o2,o3);
    P[i]=o0; P[i+4]=o1; P[i+8]=o2; P[i+12]=o3;
  }
}

// ---------------- filter generation (unchanged) ----------------
__global__ __launch_bounds__(256) void kgen_kernel(
    const float* __restrict__ W1, const float* __restrict__ b1, const float* __restrict__ fq0,
    const float* __restrict__ W2, const float* __restrict__ b2, const float* __restrict__ fq1,
    const float* __restrict__ W3, const float* __restrict__ b3, const float* __restrict__ fq2,
    const float* __restrict__ Wout, const float* __restrict__ Dv, float* __restrict__ kbuf) {
  int l = blockIdx.x * 256 + threadIdx.x;
  int c0 = blockIdx.y * 32;
  float t = (float)l * (1.0f / (float)(L_SEQ - 1));
  float w = 6.2831853071795864769f * (float)l / (float)L_SEQ;
  float z0 = t;
  float z1 = __cosf(1e-4f * w);
  float z2 = __cosf(w);
  float z3 = -__sinf(1e-4f * w);
  float z4 = -__sinf(w);
  float ha[64];
  #pragma unroll
  for (int o = 0; o < 64; ++o) {
    float acc = b1[o] + z0*W1[o*5+0] + z1*W1[o*5+1] + z2*W1[o*5+2]
                      + z3*W1[o*5+3] + z4*W1[o*5+4];
    ha[o] = __sinf(fq0[o] * acc);
  }
  float hb[64];
  #pragma unroll
  for (int p = 0; p < 64; ++p) {
    float acc = b2[p];
    #pragma unroll
    for (int o = 0; o < 64; ++o) acc += ha[o] * W2[p*64+o];
    hb[p] = __sinf(fq1[p] * acc);
  }
  #pragma unroll
  for (int p = 0; p < 64; ++p) {
    float acc = b3[p];
    #pragma unroll
    for (int o = 0; o < 64; ++o) acc += hb[o] * W3[p*64+o];
    ha[p] = __sinf(fq2[p] * acc);   // ha now holds h3
  }
  const float mind = -3.0701134573253945f;    // ln(0.01)/1.5
  const float maxd = -15.350567286626972f;    // ln(0.01)/0.3
  for (int jj = 0; jj < 32; ++jj) {
    int c = c0 + jj;
    float acc = 0.f;
    #pragma unroll
    for (int o = 0; o < 64; ++o) acc += ha[o] * Wout[c*64+o];
    float delta = mind + (maxd - mind) * ((float)c * (1.0f/255.0f));
    float dec = __expf(-t * fabsf(delta)) + 0.05f;
    float v = acc * dec;
    if (l == 0) v += Dv[c];                   // conv(u, k + D*delta) = conv + D*u
    kbuf[(size_t)c * L_SEQ + l] = v;
  }
}

// ---------------- kernel spectra: pipe A = FFT8192(k)/16384, pipe B = FFT8192(k*w16384^n)/16384 ----------------
// grid (256 channels, 2 pipes)
__global__ __launch_bounds__(NTH) void kf_kernel(const float* __restrict__ kbuf,
                                                 float2* __restrict__ Kf) {
  __shared__ float2 X[LDS_SZ];
  int c = blockIdx.x;
  int pipe = blockIdx.y;
  int tid = threadIdx.x;
  const float* kr = kbuf + (size_t)c * L_SEQ;
  const float sc = 1.0f / 16384.0f;

  // prolog: optional pre-twiddle (pipe B), then 8192-level radix-2
  #pragma unroll
  for (int r = 0; r < 2; ++r) {
    int n = 4*tid + 2048*r;
    float4 lo = *(const float4*)(kr + n);
    float4 hi = *(const float4*)(kr + n + 4096);
    #pragma unroll
    for (int j = 0; j < 4; ++j) {
      float klo = ((const float*)&lo)[j];
      float khi = ((const float*)&hi)[j];
      float2 vlo, vhi, w8;
      if (pipe == 0) {
        float sn, cn; __sincosf(-ANG8 * (float)(n+j), &sn, &cn);
        vlo = make_float2(klo, 0.f);
        vhi = make_float2(khi, 0.f);
        w8 = make_float2(cn, sn);
      } else {
        float sn, cn; __sincosf(-ANG16 * (float)(n+j), &sn, &cn);
        vlo = make_float2(klo*cn, klo*sn);          // klo * w16^n
        vhi = make_float2(khi*sn, -khi*cn);         // khi * w16^n * (-i)
        w8 = cmul(make_float2(cn, sn), make_float2(cn, sn));
      }
      X[PIDX(n+j)]        = cadd(vlo, vhi);
      X[PIDX(n+j+4096)]   = cmul(csub(vlo, vhi), w8);
    }
  }
  __syncthreads();
  fwd_pair<1024>(X, tid); __syncthreads();
  fwd_pair<64>(X, tid);   __syncthreads();
  // fused fwd(4,1) + scaled store
  {
    float2 P[16];
    int base = tid*16;
    #pragma unroll
    for (int j = 0; j < 16; ++j) P[j] = X[PIDX(base+j)];
    fwd41(P);
    float2* out = Kf + (size_t)c * 16384 + pipe*8192 + base;
    #pragma unroll
    for (int j = 0; j < 16; ++j) out[j] = make_float2(P[j].x*sc, P[j].y*sc);
  }
}

// ---------------- conv: two 8192 pipelines (odd bins then even bins), reg-stash combine ----------------
__global__ __launch_bounds__(NTH) void conv_kernel(const float* __restrict__ x,
                                                   const float2* __restrict__ Kf,
                                                   float* __restrict__ y) {
  __shared__ float2 X[LDS_SZ];
  int c = blockIdx.x;
  int p = blockIdx.y;
  int tid = threadIdx.x;
  const float* u0 = x + ((size_t)p       * HID + c) * L_SEQ;
  const float* u1 = x + ((size_t)(p + 4) * HID + c) * L_SEQ;
  const float2* KA = Kf + (size_t)c * 16384;
  const float2* KB = KA + 8192;
  float* y0 = y + ((size_t)p       * HID + c) * L_SEQ;
  float* y1 = y + ((size_t)(p + 4) * HID + c) * L_SEQ;

  float2 stash[16];   // w16384bar^n * IU_B at this thread's output positions

  // ================= pipeline B (odd bins) =================
  #pragma unroll
  for (int r = 0; r < 2; ++r) {
    int n = 4*tid + 2048*r;
    float4 a0 = *(const float4*)(u0 + n);
    float4 a1 = *(const float4*)(u1 + n);
    float4 b0 = *(const float4*)(u0 + n + 4096);
    float4 b1 = *(const float4*)(u1 + n + 4096);
    #pragma unroll
    for (int j = 0; j < 4; ++j) {
      float sn, cn; __sincosf(-ANG16 * (float)(n+j), &sn, &cn);
      float2 w16 = make_float2(cn, sn);
      float2 vlo = cmul(make_float2(((const float*)&a0)[j], ((const float*)&a1)[j]), w16);
      float2 vhi = cmul(make_float2(((const float*)&b0)[j], ((const float*)&b1)[j]),
                        make_float2(sn, -cn));        // * w16 * (-i)
      float2 w8 = cmul(w16, w16);
      X[PIDX(n+j)]      = cadd(vlo, vhi);
      X[PIDX(n+j+4096)] = cmul(csub(vlo, vhi), w8);
    }
  }
  __syncthreads();
  fwd_pair<1024>(X, tid); __syncthreads();
  fwd_pair<64>(X, tid);   __syncthreads();
  {
    float2 P[16];
    int base = tid*16;
    #pragma unroll
    for (int j = 0; j < 16; ++j) P[j] = X[PIDX(base+j)];
    fwd41(P);
    #pragma unroll
    for (int j = 0; j < 16; ++j) P[j] = cmul(P[j], KB[base+j]);
    inv14(P);
    #pragma unroll
    for (int j = 0; j < 16; ++j) X[PIDX(base+j)] = P[j];
  }
  __syncthreads();
  inv_pair<64>(X, tid);   __syncthreads();
  inv_pair<1024>(X, tid); __syncthreads();
  // epilog B: within-pipeline radix-2 inverse + cross twiddle -> stash
  #pragma unroll
  for (int r = 0; r < 2; ++r) {
    int n = 4*tid + 2048*r;
    #pragma unroll
    for (int j = 0; j < 4; ++j) {
      float2 P = X[PIDX(n+j)], Q = X[PIDX(n+j+4096)];
      float sn, cn; __sincosf(ANG16 * (float)(n+j), &sn, &cn);   // w16bar^n
      float2 w16b = make_float2(cn, sn);
      float2 w8b = cmul(w16b, w16b);
      float2 t = cmul(Q, w8b);
      float2 IUlo = cadd(P, t);
      float2 IUhi = csub(P, t);
      stash[r*4+j]     = cmul(IUlo, w16b);
      stash[8 + r*4+j] = cmul(IUhi, make_float2(-w16b.y, w16b.x));  // * i*w16bar^n
    }
  }
  __syncthreads();   // all reads done before pipeline A overwrites LDS

  // ================= pipeline A (even bins) =================
  #pragma unroll
  for (int r = 0; r < 2; ++r) {
    int n = 4*tid + 2048*r;
    float4 a0 = *(const float4*)(u0 + n);
    float4 a1 = *(const float4*)(u1 + n);
    float4 b0 = *(const float4*)(u0 + n + 4096);
    float4 b1 = *(const float4*)(u1 + n + 4096);
    #pragma unroll
    for (int j = 0; j < 4; ++j) {
      float sn, cn; __sincosf(-ANG8 * (float)(n+j), &sn, &cn);
      float2 vlo = make_float2(((const float*)&a0)[j], ((const float*)&a1)[j]);
      float2 vhi = make_float2(((const float*)&b0)[j], ((const float*)&b1)[j]);
      X[PIDX(n+j)]      = cadd(vlo, vhi);
      X[PIDX(n+j+4096)] = cmul(csub(vlo, vhi), make_float2(cn, sn));
    }
  }
  __syncthreads();
  fwd_pair<1024>(X, tid); __syncthreads();
  fwd_pair<64>(X, tid);   __syncthreads();
  {
    float2 P[16];
    int base = tid*16;
    #pragma unroll
    for (int j = 0; j < 16; ++j) P[j] = X[PIDX(base+j)];
    fwd41(P);
    #pragma unroll
    for (int j = 0; j < 16; ++j) P[j] = cmul(P[j], KA[base+j]);
    inv14(P);
    #pragma unroll
    for (int j = 0; j < 16; ++j) X[PIDX(base+j)] = P[j];
  }
  __syncthreads();
  inv_pair<64>(X, tid);   __syncthreads();
  inv_pair<1024>(X, tid); __syncthreads();
  // epilog A: radix-2 inverse + add stash, store y
  #pragma unroll
  for (int r = 0; r < 2; ++r) {
    int n = 4*tid + 2048*r;
    float4 w00, w01, w10, w11;
    #pragma unroll
    for (int j = 0; j < 4; ++j) {
      float2 P = X[PIDX(n+j)], Q = X[PIDX(n+j+4096)];
      float sn, cn; __sincosf(ANG8 * (float)(n+j), &sn, &cn);    // w8bar^n
      float2 t = cmul(Q, make_float2(cn, sn));
      float2 lo = cadd(cadd(P, t), stash[r*4+j]);
      float2 hi = cadd(csub(P, t), stash[8 + r*4+j]);
      ((float*)&w00)[j] = lo.x; ((float*)&w01)[j] = lo.y;
      ((float*)&w10)[j] = hi.x; ((float*)&w11)[j] = hi.y;
    }
    *(float4*)(y0 + n)        = w00;
    *(float4*)(y1 + n)        = w01;
    *(float4*)(y0 + n + 4096) = w10;
    *(float4*)(y1 + n + 4096) = w11;
  }
}

extern "C" void kernel_launch(void* const* d_in, const int* in_sizes, int n_in,
                              void* d_out, int out_size, void* d_ws, size_t ws_size,
                              hipStream_t stream) {
  const float* x    = (const float*)d_in[0];
  const float* W1   = (const float*)d_in[1];
  const float* b1   = (const float*)d_in[2];
  const float* fq0  = (const float*)d_in[3];
  const float* W2   = (const float*)d_in[4];
  const float* b2   = (const float*)d_in[5];
  const float* fq1  = (const float*)d_in[6];
  const float* W3   = (const float*)d_in[7];
  const float* b3   = (const float*)d_in[8];
  const float* fq2  = (const float*)d_in[9];
  const float* Wout = (const float*)d_in[10];
  const float* Dv   = (const float*)d_in[11];

  float*  kbuf = (float*)d_ws;                                                  // 8 MB
  float2* Kf   = (float2*)((char*)d_ws + (size_t)HID * L_SEQ * sizeof(float));  // +32 MB
  float*  y    = (float*)d_out;

  kgen_kernel<<<dim3(32, 8), 256, 0, stream>>>(W1,b1,fq0,W2,b2,fq1,W3,b3,fq2,Wout,Dv,kbuf);
  kf_kernel  <<<dim3(256,2), NTH, 0, stream>>>(kbuf, Kf);
  conv_kernel<<<dim3(256,4), NTH, 0, stream>>>(x, Kf, y);
}

// Round 5
// 234.099 us; speedup vs baseline: 2.5903x; 1.7068x over previous
//
#include <hip/hip_runtime.h>

#define L_SEQ 8192
#define NTH 512
#define HID 256
#define PIDX(i) ((i) + ((i) >> 5))
#define LDS_SZ 8448        // PIDX(8191)+1 = 8447, rounded

#define ANG16 3.83495196971410315e-4f   // 2*pi/16384
#define ANG8  7.66990393942820630e-4f   // 2*pi/8192

__device__ __forceinline__ float2 cmul(float2 a, float2 b) {
  return make_float2(a.x*b.x - a.y*b.y, a.x*b.y + a.y*b.x);
}
__device__ __forceinline__ float2 cadd(float2 a, float2 b){ return make_float2(a.x+b.x, a.y+b.y); }
__device__ __forceinline__ float2 csub(float2 a, float2 b){ return make_float2(a.x-b.x, a.y-b.y); }

__device__ __forceinline__ void bf4_fwd(float2 a0, float2 a1, float2 a2, float2 a3,
                                        float2& o0, float2& o1, float2& o2, float2& o3) {
  float2 t0 = cadd(a0,a2), t1 = csub(a0,a2), t2 = cadd(a1,a3), t3 = csub(a1,a3);
  o0 = cadd(t0,t2);
  o2 = csub(t0,t2);
  o1 = make_float2(t1.x + t3.y, t1.y - t3.x);   // t1 - i*t3
  o3 = make_float2(t1.x - t3.y, t1.y + t3.x);   // t1 + i*t3
}
__device__ __forceinline__ void bf4_inv(float2 c0, float2 c1, float2 c2, float2 c3,
                                        float2& o0, float2& o1, float2& o2, float2& o3) {
  float2 u0 = cadd(c0,c2), u2 = csub(c0,c2), u1 = cadd(c1,c3);
  float2 v3 = make_float2(c3.y - c1.y, c1.x - c3.x);  // i*(c1-c3)
  o0 = cadd(u0,u1); o2 = csub(u0,u1); o1 = cadd(u2,v3); o3 = csub(u2,v3);
}

// omega16^a for a=0..3 (fwd_pair/inv_pair level twiddles)
__device__ __constant__ const float W16C[4] = {1.0f, 0.92387953251128674f, 0.70710678118654752f, 0.38268343236508977f};
__device__ __constant__ const float W16S[4] = {0.0f, -0.38268343236508977f, -0.70710678118654752f, -0.92387953251128674f};
// omega16^e for e=0..9 (fused middle, exponent a*b)
__device__ __constant__ const float C16[10] = {1.0f, 0.92387953251128674f, 0.70710678118654752f, 0.38268343236508977f,
                                               0.0f, -0.38268343236508977f, -0.70710678118654752f, -0.92387953251128674f,
                                               -1.0f, -0.92387953251128674f};
__device__ __constant__ const float S16[10] = {0.0f, -0.38268343236508977f, -0.70710678118654752f, -0.92387953251128674f,
                                               -1.0f, -0.92387953251128674f, -0.70710678118654752f, -0.38268343236508977f,
                                               0.0f, 0.38268343236508977f};

// Fused pair of forward DIF radix-4 stages (m = MB, then m = MB/4) over 8192.
template<int MB>
__device__ __forceinline__ void fwd_pair(float2* __restrict__ X, int tid) {
  const int MQ = MB / 4;
  int g = tid / MQ;
  int i2 = tid - g*MQ;
  int base = g*4*MB + i2;
  float2 e[4][4];
  #pragma unroll
  for (int a = 0; a < 4; ++a)
    #pragma unroll
    for (int b = 0; b < 4; ++b)
      e[a][b] = X[PIDX(base + a*MQ + b*MB)];
  float sb, cb;
  __sincosf(-6.2831853071795864769f * (float)i2 / (float)(4*MB), &sb, &cb);
  float2 wb = make_float2(cb, sb);
  float2 f[4][4];
  #pragma unroll
  for (int a = 0; a < 4; ++a) {
    float2 wa = cmul(wb, make_float2(W16C[a], W16S[a]));
    float2 w2 = cmul(wa, wa), w3 = cmul(w2, wa);
    float2 o0,o1,o2,o3;
    bf4_fwd(e[a][0], e[a][1], e[a][2], e[a][3], o0,o1,o2,o3);
    f[a][0] = o0; f[a][1] = cmul(o1,wa); f[a][2] = cmul(o2,w2); f[a][3] = cmul(o3,w3);
  }
  float2 wp = cmul(wb,wb); wp = cmul(wp,wp);
  float2 wp2 = cmul(wp,wp), wp3 = cmul(wp2,wp);
  #pragma unroll
  for (int b = 0; b < 4; ++b) {
    float2 o0,o1,o2,o3;
    bf4_fwd(f[0][b], f[1][b], f[2][b], f[3][b], o0,o1,o2,o3);
    X[PIDX(base + 0*MQ + b*MB)] = o0;
    X[PIDX(base + 1*MQ + b*MB)] = cmul(o1,wp);
    X[PIDX(base + 2*MQ + b*MB)] = cmul(o2,wp2);
    X[PIDX(base + 3*MQ + b*MB)] = cmul(o3,wp3);
  }
}

// Fused pair of inverse DIT radix-4 stages (m = MB/4, then m = MB).
template<int MB>
__device__ __forceinline__ void inv_pair(float2* __restrict__ X, int tid) {
  const int MQ = MB / 4;
  int g = tid / MQ;
  int i2 = tid - g*MQ;
  int base = g*4*MB + i2;
  float2 e[4][4];
  #pragma unroll
  for (int a = 0; a < 4; ++a)
    #pragma unroll
    for (int b = 0; b < 4; ++b)
      e[a][b] = X[PIDX(base + a*MQ + b*MB)];
  float sb, cb;
  __sincosf(6.2831853071795864769f * (float)i2 / (float)(4*MB), &sb, &cb);
  float2 wb = make_float2(cb, sb);
  float2 wq = cmul(wb,wb); wq = cmul(wq,wq);
  float2 wq2 = cmul(wq,wq), wq3 = cmul(wq2,wq);
  float2 f[4][4];
  #pragma unroll
  for (int b = 0; b < 4; ++b) {
    float2 c0 = e[0][b];
    float2 c1 = cmul(e[1][b], wq);
    float2 c2 = cmul(e[2][b], wq2);
    float2 c3 = cmul(e[3][b], wq3);
    float2 o0,o1,o2,o3;
    bf4_inv(c0,c1,c2,c3, o0,o1,o2,o3);
    f[0][b]=o0; f[1][b]=o1; f[2][b]=o2; f[3][b]=o3;
  }
  #pragma unroll
  for (int a = 0; a < 4; ++a) {
    float2 W1 = cmul(wb, make_float2(W16C[a], -W16S[a]));
    float2 W2 = cmul(W1,W1), W3 = cmul(W2,W1);
    float2 c0 = f[a][0];
    float2 c1 = cmul(f[a][1], W1);
    float2 c2 = cmul(f[a][2], W2);
    float2 c3 = cmul(f[a][3], W3);
    float2 o0,o1,o2,o3;
    bf4_inv(c0,c1,c2,c3, o0,o1,o2,o3);
    X[PIDX(base + a*MQ + 0*MB)] = o0;
    X[PIDX(base + a*MQ + 1*MB)] = o1;
    X[PIDX(base + a*MQ + 2*MB)] = o2;
    X[PIDX(base + a*MQ + 3*MB)] = o3;
  }
}

// forward stages m=4 then m=1, compile-time twiddles, on 16 consecutive points
__device__ __forceinline__ void fwd41(float2 P[16]) {
  #pragma unroll
  for (int i = 0; i < 4; ++i) {
    float2 o0,o1,o2,o3;
    bf4_fwd(P[i], P[i+4], P[i+8], P[i+12], o0,o1,o2,o3);
    P[i]    = o0;
    P[i+4]  = cmul(o1, make_float2(C16[i],   S16[i]));
    P[i+8]  = cmul(o2, make_float2(C16[2*i], S16[2*i]));
    P[i+12] = cmul(o3, make_float2(C16[3*i], S16[3*i]));
  }
  #pragma unroll
  for (int q = 0; q < 4; ++q) {
    float2 o0,o1,o2,o3;
    bf4_fwd(P[4*q],P[4*q+1],P[4*q+2],P[4*q+3], o0,o1,o2,o3);
    P[4*q]=o0; P[4*q+1]=o1; P[4*q+2]=o2; P[4*q+3]=o3;
  }
}
// inverse stages m=1 then m=4 (exact inverse of fwd41, unnormalized x16)
__device__ __forceinline__ void inv14(float2 P[16]) {
  #pragma unroll
  for (int q = 0; q < 4; ++q) {
    float2 o0,o1,o2,o3;
    bf4_inv(P[4*q],P[4*q+1],P[4*q+2],P[4*q+3], o0,o1,o2,o3);
    P[4*q]=o0; P[4*q+1]=o1; P[4*q+2]=o2; P[4*q+3]=o3;
  }
  #pragma unroll
  for (int i = 0; i < 4; ++i) {
    float2 c0 = P[i];
    float2 c1 = cmul(P[i+4],  make_float2(C16[i],   -S16[i]));
    float2 c2 = cmul(P[i+8],  make_float2(C16[2*i], -S16[2*i]));
    float2 c3 = cmul(P[i+12], make_float2(C16[3*i], -S16[3*i]));
    float2 o0,o1,o2,o3;
    bf4_inv(c0,c1,c2,c3, o0,o1,o2,o3);
    P[i]=o0; P[i+4]=o1; P[i+8]=o2; P[i+12]=o3;
  }
}

// ---------------- filter generation (unchanged) ----------------
__global__ __launch_bounds__(256) void kgen_kernel(
    const float* __restrict__ W1, const float* __restrict__ b1, const float* __restrict__ fq0,
    const float* __restrict__ W2, const float* __restrict__ b2, const float* __restrict__ fq1,
    const float* __restrict__ W3, const float* __restrict__ b3, const float* __restrict__ fq2,
    const float* __restrict__ Wout, const float* __restrict__ Dv, float* __restrict__ kbuf) {
  int l = blockIdx.x * 256 + threadIdx.x;
  int c0 = blockIdx.y * 32;
  float t = (float)l * (1.0f / (float)(L_SEQ - 1));
  float w = 6.2831853071795864769f * (float)l / (float)L_SEQ;
  float z0 = t;
  float z1 = __cosf(1e-4f * w);
  float z2 = __cosf(w);
  float z3 = -__sinf(1e-4f * w);
  float z4 = -__sinf(w);
  float ha[64];
  #pragma unroll
  for (int o = 0; o < 64; ++o) {
    float acc = b1[o] + z0*W1[o*5+0] + z1*W1[o*5+1] + z2*W1[o*5+2]
                      + z3*W1[o*5+3] + z4*W1[o*5+4];
    ha[o] = __sinf(fq0[o] * acc);
  }
  float hb[64];
  #pragma unroll
  for (int p = 0; p < 64; ++p) {
    float acc = b2[p];
    #pragma unroll
    for (int o = 0; o < 64; ++o) acc += ha[o] * W2[p*64+o];
    hb[p] = __sinf(fq1[p] * acc);
  }
  #pragma unroll
  for (int p = 0; p < 64; ++p) {
    float acc = b3[p];
    #pragma unroll
    for (int o = 0; o < 64; ++o) acc += hb[o] * W3[p*64+o];
    ha[p] = __sinf(fq2[p] * acc);   // ha now holds h3
  }
  const float mind = -3.0701134573253945f;    // ln(0.01)/1.5
  const float maxd = -15.350567286626972f;    // ln(0.01)/0.3
  for (int jj = 0; jj < 32; ++jj) {
    int c = c0 + jj;
    float acc = 0.f;
    #pragma unroll
    for (int o = 0; o < 64; ++o) acc += ha[o] * Wout[c*64+o];
    float delta = mind + (maxd - mind) * ((float)c * (1.0f/255.0f));
    float dec = __expf(-t * fabsf(delta)) + 0.05f;
    float v = acc * dec;
    if (l == 0) v += Dv[c];                   // conv(u, k + D*delta) = conv + D*u
    kbuf[(size_t)c * L_SEQ + l] = v;
  }
}

// ---------------- kernel spectra: pipe 0 = FFT8192(k)/16384, pipe 1 = FFT8192(k*w16384^n)/16384 ----------------
// grid (256 channels, 2 pipes)
__global__ __launch_bounds__(NTH) void kf_kernel(const float* __restrict__ kbuf,
                                                 float2* __restrict__ Kf) {
  __shared__ float2 X[LDS_SZ];
  int c = blockIdx.x;
  int pipe = blockIdx.y;
  int tid = threadIdx.x;
  const float* kr = kbuf + (size_t)c * L_SEQ;
  const float sc = 1.0f / 16384.0f;

  #pragma unroll
  for (int r = 0; r < 2; ++r) {
    int n = 4*tid + 2048*r;
    float4 lo = *(const float4*)(kr + n);
    float4 hi = *(const float4*)(kr + n + 4096);
    #pragma unroll
    for (int j = 0; j < 4; ++j) {
      float klo = ((const float*)&lo)[j];
      float khi = ((const float*)&hi)[j];
      float2 vlo, vhi, w8;
      if (pipe == 0) {
        float sn, cn; __sincosf(-ANG8 * (float)(n+j), &sn, &cn);
        vlo = make_float2(klo, 0.f);
        vhi = make_float2(khi, 0.f);
        w8 = make_float2(cn, sn);
      } else {
        float sn, cn; __sincosf(-ANG16 * (float)(n+j), &sn, &cn);
        vlo = make_float2(klo*cn, klo*sn);          // klo * w16^n
        vhi = make_float2(khi*sn, -khi*cn);         // khi * w16^n * (-i)
        w8 = cmul(make_float2(cn, sn), make_float2(cn, sn));
      }
      X[PIDX(n+j)]        = cadd(vlo, vhi);
      X[PIDX(n+j+4096)]   = cmul(csub(vlo, vhi), w8);
    }
  }
  __syncthreads();
  fwd_pair<1024>(X, tid); __syncthreads();
  fwd_pair<64>(X, tid);   __syncthreads();
  {
    float2 P[16];
    int base = tid*16;
    #pragma unroll
    for (int j = 0; j < 16; ++j) P[j] = X[PIDX(base+j)];
    fwd41(P);
    float2* out = Kf + (size_t)c * 16384 + pipe*8192 + base;
    #pragma unroll
    for (int j = 0; j < 16; ++j) out[j] = make_float2(P[j].x*sc, P[j].y*sc);
  }
}

// ---------------- conv pipelines, split into two dispatches (no long-lived stash) ----------------
// PIPE=1 (odd bins): pre-twiddled 8192 pipeline; epilog writes its cross-twiddled
//                    contribution directly to y.
// PIPE=0 (even bins): plain 8192 pipeline; epilog reads y, adds, stores final.
template<int PIPE>
__global__ __launch_bounds__(NTH) void conv_pipe(const float* __restrict__ x,
                                                 const float2* __restrict__ Kf,
                                                 float* __restrict__ y) {
  __shared__ float2 X[LDS_SZ];
  int c = blockIdx.x;
  int p = blockIdx.y;
  int tid = threadIdx.x;
  const float* u0 = x + ((size_t)p       * HID + c) * L_SEQ;
  const float* u1 = x + ((size_t)(p + 4) * HID + c) * L_SEQ;
  const float2* K = Kf + (size_t)c * 16384 + PIPE*8192;
  float* y0 = y + ((size_t)p       * HID + c) * L_SEQ;
  float* y1 = y + ((size_t)(p + 4) * HID + c) * L_SEQ;

  // prolog: load, (pipe-B pre-twiddle), 8192-level radix-2
  #pragma unroll
  for (int r = 0; r < 2; ++r) {
    int n = 4*tid + 2048*r;
    float4 a0 = *(const float4*)(u0 + n);
    float4 a1 = *(const float4*)(u1 + n);
    float4 b0 = *(const float4*)(u0 + n + 4096);
    float4 b1 = *(const float4*)(u1 + n + 4096);
    #pragma unroll
    for (int j = 0; j < 4; ++j) {
      float2 vlo, vhi, w8;
      if (PIPE == 0) {
        float sn, cn; __sincosf(-ANG8 * (float)(n+j), &sn, &cn);
        vlo = make_float2(((const float*)&a0)[j], ((const float*)&a1)[j]);
        vhi = make_float2(((const float*)&b0)[j], ((const float*)&b1)[j]);
        w8 = make_float2(cn, sn);
      } else {
        float sn, cn; __sincosf(-ANG16 * (float)(n+j), &sn, &cn);
        float2 w16 = make_float2(cn, sn);
        vlo = cmul(make_float2(((const float*)&a0)[j], ((const float*)&a1)[j]), w16);
        vhi = cmul(make_float2(((const float*)&b0)[j], ((const float*)&b1)[j]),
                   make_float2(sn, -cn));        // * w16 * (-i)
        w8 = cmul(w16, w16);
      }
      X[PIDX(n+j)]      = cadd(vlo, vhi);
      X[PIDX(n+j+4096)] = cmul(csub(vlo, vhi), w8);
    }
  }
  __syncthreads();
  fwd_pair<1024>(X, tid); __syncthreads();
  fwd_pair<64>(X, tid);   __syncthreads();
  // fused middle: fwd(4,1) -> pointwise * K -> inv(1,4)
  {
    float2 P[16];
    int base = tid*16;
    #pragma unroll
    for (int j = 0; j < 16; ++j) P[j] = X[PIDX(base+j)];
    fwd41(P);
    #pragma unroll
    for (int j = 0; j < 16; ++j) P[j] = cmul(P[j], K[base+j]);
    inv14(P);
    #pragma unroll
    for (int j = 0; j < 16; ++j) X[PIDX(base+j)] = P[j];
  }
  __syncthreads();
  inv_pair<64>(X, tid);   __syncthreads();
  inv_pair<1024>(X, tid); __syncthreads();
  // epilog: within-pipeline radix-2 inverse, cross twiddle, store (B) / accumulate (A)
  #pragma unroll
  for (int r = 0; r < 2; ++r) {
    int n = 4*tid + 2048*r;
    float4 w00, w01, w10, w11;
    #pragma unroll
    for (int j = 0; j < 4; ++j) {
      float2 P = X[PIDX(n+j)], Q = X[PIDX(n+j+4096)];
      float2 lo, hi;
      if (PIPE == 1) {
        float sn, cn; __sincosf(ANG16 * (float)(n+j), &sn, &cn);   // w16384bar^n
        float2 w16b = make_float2(cn, sn);
        float2 w8b = cmul(w16b, w16b);
        float2 t = cmul(Q, w8b);
        lo = cmul(cadd(P, t), w16b);
        hi = cmul(csub(P, t), make_float2(-w16b.y, w16b.x));       // * i*w16bar^n
      } else {
        float sn, cn; __sincosf(ANG8 * (float)(n+j), &sn, &cn);    // w8192bar^n
        float2 t = cmul(Q, make_float2(cn, sn));
        lo = cadd(P, t);
        hi = csub(P, t);
      }
      ((float*)&w00)[j] = lo.x; ((float*)&w01)[j] = lo.y;
      ((float*)&w10)[j] = hi.x; ((float*)&w11)[j] = hi.y;
    }
    if (PIPE == 0) {   // accumulate partial written by pipe B
      float4 p00 = *(const float4*)(y0 + n);
      float4 p01 = *(const float4*)(y1 + n);
      float4 p10 = *(const float4*)(y0 + n + 4096);
      float4 p11 = *(const float4*)(y1 + n + 4096);
      w00.x += p00.x; w00.y += p00.y; w00.z += p00.z; w00.w += p00.w;
      w01.x += p01.x; w01.y += p01.y; w01.z += p01.z; w01.w += p01.w;
      w10.x += p10.x; w10.y += p10.y; w10.z += p10.z; w10.w += p10.w;
      w11.x += p11.x; w11.y += p11.y; w11.z += p11.z; w11.w += p11.w;
    }
    *(float4*)(y0 + n)        = w00;
    *(float4*)(y1 + n)        = w01;
    *(float4*)(y0 + n + 4096) = w10;
    *(float4*)(y1 + n + 4096) = w11;
  }
}

extern "C" void kernel_launch(void* const* d_in, const int* in_sizes, int n_in,
                              void* d_out, int out_size, void* d_ws, size_t ws_size,
                              hipStream_t stream) {
  const float* x    = (const float*)d_in[0];
  const float* W1   = (const float*)d_in[1];
  const float* b1   = (const float*)d_in[2];
  const float* fq0  = (const float*)d_in[3];
  const float* W2   = (const float*)d_in[4];
  const float* b2   = (const float*)d_in[5];
  const float* fq1  = (const float*)d_in[6];
  const float* W3   = (const float*)d_in[7];
  const float* b3   = (const float*)d_in[8];
  const float* fq2  = (const float*)d_in[9];
  const float* Wout = (const float*)d_in[10];
  const float* Dv   = (const float*)d_in[11];

  float*  kbuf = (float*)d_ws;                                                  // 8 MB
  float2* Kf   = (float2*)((char*)d_ws + (size_t)HID * L_SEQ * sizeof(float));  // +32 MB
  float*  y    = (float*)d_out;

  kgen_kernel <<<dim3(32, 8), 256, 0, stream>>>(W1,b1,fq0,W2,b2,fq1,W3,b3,fq2,Wout,Dv,kbuf);
  kf_kernel   <<<dim3(256,2), NTH, 0, stream>>>(kbuf, Kf);
  conv_pipe<1><<<dim3(256,4), NTH, 0, stream>>>(x, Kf, y);   // odd bins: write partial
  conv_pipe<0><<<dim3(256,4), NTH, 0, stream>>>(x, Kf, y);   // even bins: accumulate
}

// Round 6
// 172.560 us; speedup vs baseline: 3.5141x; 1.3566x over previous
//
#include <hip/hip_runtime.h>

#define L_SEQ 8192
#define NTH 512
#define HID 256
#define PIDX(i) ((i) + ((i) >> 5))
#define LDS_SZ 8448        // PIDX(8191)+1 = 8447, rounded

#define ANG16 3.83495196971410315e-4f   // 2*pi/16384
#define ANG8  7.66990393942820630e-4f   // 2*pi/8192

__device__ __forceinline__ float2 cmul(float2 a, float2 b) {
  return make_float2(a.x*b.x - a.y*b.y, a.x*b.y + a.y*b.x);
}
__device__ __forceinline__ float2 cadd(float2 a, float2 b){ return make_float2(a.x+b.x, a.y+b.y); }
__device__ __forceinline__ float2 csub(float2 a, float2 b){ return make_float2(a.x-b.x, a.y-b.y); }

__device__ __forceinline__ void bf4_fwd(float2 a0, float2 a1, float2 a2, float2 a3,
                                        float2& o0, float2& o1, float2& o2, float2& o3) {
  float2 t0 = cadd(a0,a2), t1 = csub(a0,a2), t2 = cadd(a1,a3), t3 = csub(a1,a3);
  o0 = cadd(t0,t2);
  o2 = csub(t0,t2);
  o1 = make_float2(t1.x + t3.y, t1.y - t3.x);   // t1 - i*t3
  o3 = make_float2(t1.x - t3.y, t1.y + t3.x);   // t1 + i*t3
}
__device__ __forceinline__ void bf4_inv(float2 c0, float2 c1, float2 c2, float2 c3,
                                        float2& o0, float2& o1, float2& o2, float2& o3) {
  float2 u0 = cadd(c0,c2), u2 = csub(c0,c2), u1 = cadd(c1,c3);
  float2 v3 = make_float2(c3.y - c1.y, c1.x - c3.x);  // i*(c1-c3)
  o0 = cadd(u0,u1); o2 = csub(u0,u1); o1 = cadd(u2,v3); o3 = csub(u2,v3);
}

// omega16^a for a=0..3 (fwd_pair/inv_pair level twiddles)
__device__ __constant__ const float W16C[4] = {1.0f, 0.92387953251128674f, 0.70710678118654752f, 0.38268343236508977f};
__device__ __constant__ const float W16S[4] = {0.0f, -0.38268343236508977f, -0.70710678118654752f, -0.92387953251128674f};
// omega16^e for e=0..9 (fused middle, exponent a*b)
__device__ __constant__ const float C16[10] = {1.0f, 0.92387953251128674f, 0.70710678118654752f, 0.38268343236508977f,
                                               0.0f, -0.38268343236508977f, -0.70710678118654752f, -0.92387953251128674f,
                                               -1.0f, -0.92387953251128674f};
__device__ __constant__ const float S16[10] = {0.0f, -0.38268343236508977f, -0.70710678118654752f, -0.92387953251128674f,
                                               -1.0f, -0.92387953251128674f, -0.70710678118654752f, -0.38268343236508977f,
                                               0.0f, 0.38268343236508977f};

// Fused pair of forward DIF radix-4 stages (m = MB, then m = MB/4) over 8192.
template<int MB>
__device__ __forceinline__ void fwd_pair(float2* __restrict__ X, int tid) {
  const int MQ = MB / 4;
  int g = tid / MQ;
  int i2 = tid - g*MQ;
  int base = g*4*MB + i2;
  float2 e[4][4];
  #pragma unroll
  for (int a = 0; a < 4; ++a)
    #pragma unroll
    for (int b = 0; b < 4; ++b)
      e[a][b] = X[PIDX(base + a*MQ + b*MB)];
  float sb, cb;
  __sincosf(-6.2831853071795864769f * (float)i2 / (float)(4*MB), &sb, &cb);
  float2 wb = make_float2(cb, sb);
  float2 f[4][4];
  #pragma unroll
  for (int a = 0; a < 4; ++a) {
    float2 wa = cmul(wb, make_float2(W16C[a], W16S[a]));
    float2 w2 = cmul(wa, wa), w3 = cmul(w2, wa);
    float2 o0,o1,o2,o3;
    bf4_fwd(e[a][0], e[a][1], e[a][2], e[a][3], o0,o1,o2,o3);
    f[a][0] = o0; f[a][1] = cmul(o1,wa); f[a][2] = cmul(o2,w2); f[a][3] = cmul(o3,w3);
  }
  float2 wp = cmul(wb,wb); wp = cmul(wp,wp);
  float2 wp2 = cmul(wp,wp), wp3 = cmul(wp2,wp);
  #pragma unroll
  for (int b = 0; b < 4; ++b) {
    float2 o0,o1,o2,o3;
    bf4_fwd(f[0][b], f[1][b], f[2][b], f[3][b], o0,o1,o2,o3);
    X[PIDX(base + 0*MQ + b*MB)] = o0;
    X[PIDX(base + 1*MQ + b*MB)] = cmul(o1,wp);
    X[PIDX(base + 2*MQ + b*MB)] = cmul(o2,wp2);
    X[PIDX(base + 3*MQ + b*MB)] = cmul(o3,wp3);
  }
}

// Fused pair of inverse DIT radix-4 stages (m = MB/4, then m = MB).
template<int MB>
__device__ __forceinline__ void inv_pair(float2* __restrict__ X, int tid) {
  const int MQ = MB / 4;
  int g = tid / MQ;
  int i2 = tid - g*MQ;
  int base = g*4*MB + i2;
  float2 e[4][4];
  #pragma unroll
  for (int a = 0; a < 4; ++a)
    #pragma unroll
    for (int b = 0; b < 4; ++b)
      e[a][b] = X[PIDX(base + a*MQ + b*MB)];
  float sb, cb;
  __sincosf(6.2831853071795864769f * (float)i2 / (float)(4*MB), &sb, &cb);
  float2 wb = make_float2(cb, sb);
  float2 wq = cmul(wb,wb); wq = cmul(wq,wq);
  float2 wq2 = cmul(wq,wq), wq3 = cmul(wq2,wq);
  float2 f[4][4];
  #pragma unroll
  for (int b = 0; b < 4; ++b) {
    float2 c0 = e[0][b];
    float2 c1 = cmul(e[1][b], wq);
    float2 c2 = cmul(e[2][b], wq2);
    float2 c3 = cmul(e[3][b], wq3);
    float2 o0,o1,o2,o3;
    bf4_inv(c0,c1,c2,c3, o0,o1,o2,o3);
    f[0][b]=o0; f[1][b]=o1; f[2][b]=o2; f[3][b]=o3;
  }
  #pragma unroll
  for (int a = 0; a < 4; ++a) {
    float2 W1 = cmul(wb, make_float2(W16C[a], -W16S[a]));
    float2 W2 = cmul(W1,W1), W3 = cmul(W2,W1);
    float2 c0 = f[a][0];
    float2 c1 = cmul(f[a][1], W1);
    float2 c2 = cmul(f[a][2], W2);
    float2 c3 = cmul(f[a][3], W3);
    float2 o0,o1,o2,o3;
    bf4_inv(c0,c1,c2,c3, o0,o1,o2,o3);
    X[PIDX(base + a*MQ + 0*MB)] = o0;
    X[PIDX(base + a*MQ + 1*MB)] = o1;
    X[PIDX(base + a*MQ + 2*MB)] = o2;
    X[PIDX(base + a*MQ + 3*MB)] = o3;
  }
}

// forward stages m=4 then m=1, compile-time twiddles, on 16 consecutive points
__device__ __forceinline__ void fwd41(float2 P[16]) {
  #pragma unroll
  for (int i = 0; i < 4; ++i) {
    float2 o0,o1,o2,o3;
    bf4_fwd(P[i], P[i+4], P[i+8], P[i+12], o0,o1,o2,o3);
    P[i]    = o0;
    P[i+4]  = cmul(o1, make_float2(C16[i],   S16[i]));
    P[i+8]  = cmul(o2, make_float2(C16[2*i], S16[2*i]));
    P[i+12] = cmul(o3, make_float2(C16[3*i], S16[3*i]));
  }
  #pragma unroll
  for (int q = 0; q < 4; ++q) {
    float2 o0,o1,o2,o3;
    bf4_fwd(P[4*q],P[4*q+1],P[4*q+2],P[4*q+3], o0,o1,o2,o3);
    P[4*q]=o0; P[4*q+1]=o1; P[4*q+2]=o2; P[4*q+3]=o3;
  }
}
// inverse stages m=1 then m=4 (exact inverse of fwd41, unnormalized x16)
__device__ __forceinline__ void inv14(float2 P[16]) {
  #pragma unroll
  for (int q = 0; q < 4; ++q) {
    float2 o0,o1,o2,o3;
    bf4_inv(P[4*q],P[4*q+1],P[4*q+2],P[4*q+3], o0,o1,o2,o3);
    P[4*q]=o0; P[4*q+1]=o1; P[4*q+2]=o2; P[4*q+3]=o3;
  }
  #pragma unroll
  for (int i = 0; i < 4; ++i) {
    float2 c0 = P[i];
    float2 c1 = cmul(P[i+4],  make_float2(C16[i],   -S16[i]));
    float2 c2 = cmul(P[i+8],  make_float2(C16[2*i], -S16[2*i]));
    float2 c3 = cmul(P[i+12], make_float2(C16[3*i], -S16[3*i]));
    float2 o0,o1,o2,o3;
    bf4_inv(c0,c1,c2,c3, o0,o1,o2,o3);
    P[i]=o0; P[i+4]=o1; P[i+8]=o2; P[i+12]=o3;
  }
}

// ---------------- MLP: h3[l, 64] for all 8192 l ----------------
// Block = 256 threads = 4 waves; wave w handles l = l0 + w + 4r (r=0..3).
// Lane = neuron index. Weights: 64 regs/lane; activations broadcast from LDS.
__global__ __launch_bounds__(256) void mlp_kernel(
    const float* __restrict__ W1, const float* __restrict__ b1, const float* __restrict__ fq0,
    const float* __restrict__ W2, const float* __restrict__ b2, const float* __restrict__ fq1,
    const float* __restrict__ W3, const float* __restrict__ b3, const float* __restrict__ fq2,
    float* __restrict__ h3g) {
  __shared__ float hs[2][16][64];
  int tid = threadIdx.x;
  int lane = tid & 63, w = tid >> 6;
  int l0 = blockIdx.x * 16;

  // layer 1: h1[l][lane]
  float w1r[5];
  #pragma unroll
  for (int e = 0; e < 5; ++e) w1r[e] = W1[lane*5+e];
  float b1v = b1[lane], f0 = fq0[lane];
  #pragma unroll
  for (int r = 0; r < 4; ++r) {
    int l = l0 + w + 4*r;
    float t = (float)l * (1.0f / (float)(L_SEQ - 1));
    float ang = 6.2831853071795864769f * (float)l / (float)L_SEQ;
    float s0, c0, s1, c1;
    __sincosf(1e-4f * ang, &s0, &c0);
    __sincosf(ang, &s1, &c1);
    float acc = b1v + t*w1r[0] + c0*w1r[1] + c1*w1r[2] - s0*w1r[3] - s1*w1r[4];
    hs[0][w + 4*r][lane] = __sinf(f0 * acc);
  }
  __syncthreads();

  // layer 2
  float wr[64];
  #pragma unroll
  for (int j = 0; j < 16; ++j) *(float4*)&wr[4*j] = *(const float4*)&W2[lane*64 + 4*j];
  float b2v = b2[lane], f1 = fq1[lane];
  #pragma unroll
  for (int r = 0; r < 4; ++r) {
    int ll = w + 4*r;
    float a0 = 0.f, a1 = 0.f, a2 = 0.f, a3 = 0.f;
    #pragma unroll
    for (int o = 0; o < 64; o += 4) {
      a0 += hs[0][ll][o+0] * wr[o+0];
      a1 += hs[0][ll][o+1] * wr[o+1];
      a2 += hs[0][ll][o+2] * wr[o+2];
      a3 += hs[0][ll][o+3] * wr[o+3];
    }
    hs[1][ll][lane] = __sinf(f1 * (b2v + ((a0+a1)+(a2+a3))));
  }
  __syncthreads();

  // layer 3 -> global (coalesced: lanes contiguous)
  #pragma unroll
  for (int j = 0; j < 16; ++j) *(float4*)&wr[4*j] = *(const float4*)&W3[lane*64 + 4*j];
  float b3v = b3[lane], f2 = fq2[lane];
  #pragma unroll
  for (int r = 0; r < 4; ++r) {
    int ll = w + 4*r;
    float a0 = 0.f, a1 = 0.f, a2 = 0.f, a3 = 0.f;
    #pragma unroll
    for (int o = 0; o < 64; o += 4) {
      a0 += hs[1][ll][o+0] * wr[o+0];
      a1 += hs[1][ll][o+1] * wr[o+1];
      a2 += hs[1][ll][o+2] * wr[o+2];
      a3 += hs[1][ll][o+3] * wr[o+3];
    }
    h3g[(size_t)(l0 + ll) * 64 + lane] = __sinf(f2 * (b3v + ((a0+a1)+(a2+a3))));
  }
}

// ---------------- k[c,l] = h3[l,:]·Wout[c,:] * decay(c,l) (+D at l=0) ----------------
// grid (32 l-chunks, 8 c-chunks) x 256 threads; thread = one l, 32 channels.
__global__ __launch_bounds__(256) void kwrite_kernel(const float* __restrict__ h3g,
                                                     const float* __restrict__ Wout,
                                                     const float* __restrict__ Dv,
                                                     float* __restrict__ kbuf) {
  __shared__ float tileh[256][65];   // padded: bank = (l + o) % 32
  int tid = threadIdx.x;
  int l0 = blockIdx.x * 256;
  int c0 = blockIdx.y * 32;
  // stage h3 tile coalesced: 256 rows x 64
  {
    const float4* src = (const float4*)(h3g + (size_t)l0 * 64);
    #pragma unroll
    for (int q = 0; q < 16; ++q) {
      int idx = tid + 256*q;          // float4 index within tile
      int row = idx >> 4, col4 = idx & 15;
      float4 v = src[idx];
      tileh[row][col4*4+0] = v.x;
      tileh[row][col4*4+1] = v.y;
      tileh[row][col4*4+2] = v.z;
      tileh[row][col4*4+3] = v.w;
    }
  }
  __syncthreads();
  float hr[64];
  #pragma unroll
  for (int o = 0; o < 64; ++o) hr[o] = tileh[tid][o];
  int l = l0 + tid;
  float t = (float)l * (1.0f / (float)(L_SEQ - 1));
  const float mind = -3.0701134573253945f;    // ln(0.01)/1.5
  const float maxd = -15.350567286626972f;    // ln(0.01)/0.3
  for (int jj = 0; jj < 32; ++jj) {
    int c = c0 + jj;
    float a0 = 0.f, a1 = 0.f, a2 = 0.f, a3 = 0.f;
    #pragma unroll
    for (int o = 0; o < 64; o += 4) {
      a0 += hr[o+0] * Wout[c*64+o+0];
      a1 += hr[o+1] * Wout[c*64+o+1];
      a2 += hr[o+2] * Wout[c*64+o+2];
      a3 += hr[o+3] * Wout[c*64+o+3];
    }
    float acc = (a0+a1)+(a2+a3);
    float delta = mind + (maxd - mind) * ((float)c * (1.0f/255.0f));
    float dec = __expf(-t * fabsf(delta)) + 0.05f;
    float v = acc * dec;
    if (l == 0) v += Dv[c];                   // conv(u, k + D*delta) = conv + D*u
    kbuf[(size_t)c * L_SEQ + l] = v;
  }
}

// ---------------- kernel spectra: pipe 0 = FFT8192(k)/16384, pipe 1 = FFT8192(k*w16384^n)/16384 ----------------
__global__ __launch_bounds__(NTH) void kf_kernel(const float* __restrict__ kbuf,
                                                 float2* __restrict__ Kf) {
  __shared__ float2 X[LDS_SZ];
  int c = blockIdx.x;
  int pipe = blockIdx.y;
  int tid = threadIdx.x;
  const float* kr = kbuf + (size_t)c * L_SEQ;
  const float sc = 1.0f / 16384.0f;

  #pragma unroll
  for (int r = 0; r < 2; ++r) {
    int n = 4*tid + 2048*r;
    float4 lo = *(const float4*)(kr + n);
    float4 hi = *(const float4*)(kr + n + 4096);
    #pragma unroll
    for (int j = 0; j < 4; ++j) {
      float klo = ((const float*)&lo)[j];
      float khi = ((const float*)&hi)[j];
      float2 vlo, vhi, w8;
      if (pipe == 0) {
        float sn, cn; __sincosf(-ANG8 * (float)(n+j), &sn, &cn);
        vlo = make_float2(klo, 0.f);
        vhi = make_float2(khi, 0.f);
        w8 = make_float2(cn, sn);
      } else {
        float sn, cn; __sincosf(-ANG16 * (float)(n+j), &sn, &cn);
        vlo = make_float2(klo*cn, klo*sn);          // klo * w16^n
        vhi = make_float2(khi*sn, -khi*cn);         // khi * w16^n * (-i)
        w8 = cmul(make_float2(cn, sn), make_float2(cn, sn));
      }
      X[PIDX(n+j)]        = cadd(vlo, vhi);
      X[PIDX(n+j+4096)]   = cmul(csub(vlo, vhi), w8);
    }
  }
  __syncthreads();
  fwd_pair<1024>(X, tid); __syncthreads();
  fwd_pair<64>(X, tid);   __syncthreads();
  {
    float2 P[16];
    int base = tid*16;
    #pragma unroll
    for (int j = 0; j < 16; ++j) P[j] = X[PIDX(base+j)];
    fwd41(P);
    float2* out = Kf + (size_t)c * 16384 + pipe*8192 + base;
    #pragma unroll
    for (int j = 0; j < 16; ++j) out[j] = make_float2(P[j].x*sc, P[j].y*sc);
  }
}

// ---------------- conv pipelines, split into two dispatches (no long-lived stash) ----------------
template<int PIPE>
__global__ __launch_bounds__(NTH) void conv_pipe(const float* __restrict__ x,
                                                 const float2* __restrict__ Kf,
                                                 float* __restrict__ y) {
  __shared__ float2 X[LDS_SZ];
  int c = blockIdx.x;
  int p = blockIdx.y;
  int tid = threadIdx.x;
  const float* u0 = x + ((size_t)p       * HID + c) * L_SEQ;
  const float* u1 = x + ((size_t)(p + 4) * HID + c) * L_SEQ;
  const float2* K = Kf + (size_t)c * 16384 + PIPE*8192;
  float* y0 = y + ((size_t)p       * HID + c) * L_SEQ;
  float* y1 = y + ((size_t)(p + 4) * HID + c) * L_SEQ;

  #pragma unroll
  for (int r = 0; r < 2; ++r) {
    int n = 4*tid + 2048*r;
    float4 a0 = *(const float4*)(u0 + n);
    float4 a1 = *(const float4*)(u1 + n);
    float4 b0 = *(const float4*)(u0 + n + 4096);
    float4 b1 = *(const float4*)(u1 + n + 4096);
    #pragma unroll
    for (int j = 0; j < 4; ++j) {
      float2 vlo, vhi, w8;
      if (PIPE == 0) {
        float sn, cn; __sincosf(-ANG8 * (float)(n+j), &sn, &cn);
        vlo = make_float2(((const float*)&a0)[j], ((const float*)&a1)[j]);
        vhi = make_float2(((const float*)&b0)[j], ((const float*)&b1)[j]);
        w8 = make_float2(cn, sn);
      } else {
        float sn, cn; __sincosf(-ANG16 * (float)(n+j), &sn, &cn);
        float2 w16 = make_float2(cn, sn);
        vlo = cmul(make_float2(((const float*)&a0)[j], ((const float*)&a1)[j]), w16);
        vhi = cmul(make_float2(((const float*)&b0)[j], ((const float*)&b1)[j]),
                   make_float2(sn, -cn));        // * w16 * (-i)
        w8 = cmul(w16, w16);
      }
      X[PIDX(n+j)]      = cadd(vlo, vhi);
      X[PIDX(n+j+4096)] = cmul(csub(vlo, vhi), w8);
    }
  }
  __syncthreads();
  fwd_pair<1024>(X, tid); __syncthreads();
  fwd_pair<64>(X, tid);   __syncthreads();
  {
    float2 P[16];
    int base = tid*16;
    #pragma unroll
    for (int j = 0; j < 16; ++j) P[j] = X[PIDX(base+j)];
    fwd41(P);
    #pragma unroll
    for (int j = 0; j < 16; ++j) P[j] = cmul(P[j], K[base+j]);
    inv14(P);
    #pragma unroll
    for (int j = 0; j < 16; ++j) X[PIDX(base+j)] = P[j];
  }
  __syncthreads();
  inv_pair<64>(X, tid);   __syncthreads();
  inv_pair<1024>(X, tid); __syncthreads();
  #pragma unroll
  for (int r = 0; r < 2; ++r) {
    int n = 4*tid + 2048*r;
    float4 w00, w01, w10, w11;
    #pragma unroll
    for (int j = 0; j < 4; ++j) {
      float2 P = X[PIDX(n+j)], Q = X[PIDX(n+j+4096)];
      float2 lo, hi;
      if (PIPE == 1) {
        float sn, cn; __sincosf(ANG16 * (float)(n+j), &sn, &cn);   // w16384bar^n
        float2 w16b = make_float2(cn, sn);
        float2 w8b = cmul(w16b, w16b);
        float2 t = cmul(Q, w8b);
        lo = cmul(cadd(P, t), w16b);
        hi = cmul(csub(P, t), make_float2(-w16b.y, w16b.x));       // * i*w16bar^n
      } else {
        float sn, cn; __sincosf(ANG8 * (float)(n+j), &sn, &cn);    // w8192bar^n
        float2 t = cmul(Q, make_float2(cn, sn));
        lo = cadd(P, t);
        hi = csub(P, t);
      }
      ((float*)&w00)[j] = lo.x; ((float*)&w01)[j] = lo.y;
      ((float*)&w10)[j] = hi.x; ((float*)&w11)[j] = hi.y;
    }
    if (PIPE == 0) {   // accumulate partial written by pipe 1
      float4 p00 = *(const float4*)(y0 + n);
      float4 p01 = *(const float4*)(y1 + n);
      float4 p10 = *(const float4*)(y0 + n + 4096);
      float4 p11 = *(const float4*)(y1 + n + 4096);
      w00.x += p00.x; w00.y += p00.y; w00.z += p00.z; w00.w += p00.w;
      w01.x += p01.x; w01.y += p01.y; w01.z += p01.z; w01.w += p01.w;
      w10.x += p10.x; w10.y += p10.y; w10.z += p10.z; w10.w += p10.w;
      w11.x += p11.x; w11.y += p11.y; w11.z += p11.z; w11.w += p11.w;
    }
    *(float4*)(y0 + n)        = w00;
    *(float4*)(y1 + n)        = w01;
    *(float4*)(y0 + n + 4096) = w10;
    *(float4*)(y1 + n + 4096) = w11;
  }
}

extern "C" void kernel_launch(void* const* d_in, const int* in_sizes, int n_in,
                              void* d_out, int out_size, void* d_ws, size_t ws_size,
                              hipStream_t stream) {
  const float* x    = (const float*)d_in[0];
  const float* W1   = (const float*)d_in[1];
  const float* b1   = (const float*)d_in[2];
  const float* fq0  = (const float*)d_in[3];
  const float* W2   = (const float*)d_in[4];
  const float* b2   = (const float*)d_in[5];
  const float* fq1  = (const float*)d_in[6];
  const float* W3   = (const float*)d_in[7];
  const float* b3   = (const float*)d_in[8];
  const float* fq2  = (const float*)d_in[9];
  const float* Wout = (const float*)d_in[10];
  const float* Dv   = (const float*)d_in[11];

  // ws layout: [0,8)MB kbuf ; [8,40)MB Kf. h3 (2 MB) aliases the TAIL of Kf:
  // written by mlp, read by kwrite, then overwritten by kf (stream-ordered).
  float*  kbuf = (float*)d_ws;
  float2* Kf   = (float2*)((char*)d_ws + (size_t)HID * L_SEQ * sizeof(float));
  float*  h3g  = (float*)((char*)d_ws + 38ull*1024*1024);
  float*  y    = (float*)d_out;

  mlp_kernel   <<<dim3(512),    256, 0, stream>>>(W1,b1,fq0,W2,b2,fq1,W3,b3,fq2,h3g);
  kwrite_kernel<<<dim3(32, 8),  256, 0, stream>>>(h3g, Wout, Dv, kbuf);
  kf_kernel    <<<dim3(256,2),  NTH, 0, stream>>>(kbuf, Kf);
  conv_pipe<1> <<<dim3(256,4),  NTH, 0, stream>>>(x, Kf, y);   // odd bins: write partial
  conv_pipe<0> <<<dim3(256,4),  NTH, 0, stream>>>(x, Kf, y);   // even bins: accumulate
}